// Round 3
// baseline (1036.505 us; speedup 1.0000x reference)
//
#include <hip/hip_runtime.h>

#define B_ 8
#define S_ 1025
#define E_ 768
#define H_ 12
#define D_ 64
#define N_ 1024
#define M_OUT (B_*S_)   // 8200

typedef _Float16 half8_t __attribute__((ext_vector_type(8)));
typedef _Float16 half4_t __attribute__((ext_vector_type(4)));
typedef short short8_t __attribute__((ext_vector_type(8)));
typedef float f32x4 __attribute__((ext_vector_type(4)));

#define MFMA_F16(A, B, C)  __builtin_amdgcn_mfma_f32_16x16x32_f16((A), (B), (C), 0, 0, 0)
#define MFMA_BF16(A, B, C) __builtin_amdgcn_mfma_f32_16x16x32_bf16((A), (B), (C), 0, 0, 0)

__device__ __forceinline__ unsigned short f2bf(float f) {
  unsigned u = __float_as_uint(f);
  u += 0x7FFFu + ((u >> 16) & 1u);          // RNE
  return (unsigned short)(u >> 16);
}
__device__ __forceinline__ float bf2f(unsigned short s) {
  return __uint_as_float(((unsigned)s) << 16);
}

// ---------------- split x (xt rows, compact) into f16 hi/lo planes ----------
__global__ __launch_bounds__(256) void split_x_kernel(
    const float* __restrict__ x, _Float16* __restrict__ xh, _Float16* __restrict__ xl)
{
  const int idx = blockIdx.x * 256 + threadIdx.x;   // 8192*192 float4s exactly
  const int row = idx / 192;
  const int c   = (idx % 192) * 4;
  const int xrow = row + (row >> 10) + 1;           // skip cls token per batch
  float4 v = *(const float4*)&x[(long)xrow*E_ + c];
  float f[4] = {v.x, v.y, v.z, v.w};
  half4_t hs, ls;
  #pragma unroll
  for (int t = 0; t < 4; ++t) {
    _Float16 hh = (_Float16)f[t];
    hs[t] = hh; ls[t] = (_Float16)(f[t] - (float)hh);
  }
  *(half4_t*)&xh[(long)row*E_ + c] = hs;
  *(half4_t*)&xl[(long)row*E_ + c] = ls;
}

// ---------------- split 4 weight matrices into f16 hi/lo planes -------------
__global__ __launch_bounds__(256) void split_w_kernel(
    const float* __restrict__ W0, const float* __restrict__ W1,
    const float* __restrict__ W2, const float* __restrict__ W3,
    _Float16* __restrict__ h0, _Float16* __restrict__ l0,
    _Float16* __restrict__ h1, _Float16* __restrict__ l1,
    _Float16* __restrict__ h2, _Float16* __restrict__ l2,
    _Float16* __restrict__ h3, _Float16* __restrict__ l3)
{
  const int which = blockIdx.y;
  const float* __restrict__ W = (which==0)?W0:(which==1)?W1:(which==2)?W2:W3;
  _Float16* __restrict__ oh   = (which==0)?h0:(which==1)?h1:(which==2)?h2:h3;
  _Float16* __restrict__ ol   = (which==0)?l0:(which==1)?l1:(which==2)?l2:l3;
  const int idx = blockIdx.x * 256 + threadIdx.x;   // 768*192 float4s exactly
  const long off = (long)idx * 4;
  float4 v = *(const float4*)&W[off];
  float f[4] = {v.x, v.y, v.z, v.w};
  half4_t hs, ls;
  #pragma unroll
  for (int t = 0; t < 4; ++t) {
    _Float16 hh = (_Float16)f[t];
    hs[t] = hh; ls[t] = (_Float16)(f[t] - (float)hh);
  }
  *(half4_t*)&oh[off] = hs;
  *(half4_t*)&ol[off] = ls;
}

// ---------------- QKV projection from f16 planes; split-format outputs ------
// q,k -> f16 hi/lo planes [row][c]; v -> bf16 hi/lo planes transposed [bh][d][n]
__global__ __launch_bounds__(256) void proj_qkv_kernel(
    const _Float16* __restrict__ xh, const _Float16* __restrict__ xl,
    const _Float16* __restrict__ wqh, const _Float16* __restrict__ wql,
    const _Float16* __restrict__ wkh, const _Float16* __restrict__ wkl,
    const _Float16* __restrict__ wvh, const _Float16* __restrict__ wvl,
    const float* __restrict__ bq, const float* __restrict__ bk, const float* __restrict__ bv,
    _Float16* __restrict__ qh, _Float16* __restrict__ ql,
    _Float16* __restrict__ kh, _Float16* __restrict__ kl,
    unsigned short* __restrict__ vth, unsigned short* __restrict__ vtl)
{
  __shared__ _Float16 Ah[128][40];
  __shared__ _Float16 Al[128][40];
  __shared__ _Float16 Bh[128][40];
  __shared__ _Float16 Bl[128][40];

  const int which = blockIdx.z;
  const _Float16* __restrict__ wh = (which==0)?wqh:(which==1)?wkh:wvh;
  const _Float16* __restrict__ wl = (which==0)?wql:(which==1)?wkl:wvl;
  const float* __restrict__ bias  = (which==0)?bq:(which==1)?bk:bv;

  const int tid  = threadIdx.x;
  const int lane = tid & 63;
  const int wv   = tid >> 6;
  const int wm   = wv >> 1, wn = wv & 1;
  const int m0   = blockIdx.y * 128;
  const int n0   = blockIdx.x * 128;

  const int srow = tid >> 1;
  const int scol = (tid & 1) << 4;

  const long arow = (long)(m0 + srow) * E_ + scol;
  const long brow = (long)(n0 + srow) * E_ + scol;

  f32x4 acc[4][4] = {};

  const int fr = lane & 15;
  const int kb = (lane >> 4) << 3;
  const int ar0 = wm * 64 + fr;
  const int br0 = wn * 64 + fr;

  for (int k0 = 0; k0 < E_; k0 += 32) {
    half8_t a_h0 = *(const half8_t*)&xh[arow + k0];
    half8_t a_h1 = *(const half8_t*)&xh[arow + k0 + 8];
    half8_t a_l0 = *(const half8_t*)&xl[arow + k0];
    half8_t a_l1 = *(const half8_t*)&xl[arow + k0 + 8];
    half8_t b_h0 = *(const half8_t*)&wh[brow + k0];
    half8_t b_h1 = *(const half8_t*)&wh[brow + k0 + 8];
    half8_t b_l0 = *(const half8_t*)&wl[brow + k0];
    half8_t b_l1 = *(const half8_t*)&wl[brow + k0 + 8];
    __syncthreads();
    *(half8_t*)&Ah[srow][scol]   = a_h0;  *(half8_t*)&Ah[srow][scol+8] = a_h1;
    *(half8_t*)&Al[srow][scol]   = a_l0;  *(half8_t*)&Al[srow][scol+8] = a_l1;
    *(half8_t*)&Bh[srow][scol]   = b_h0;  *(half8_t*)&Bh[srow][scol+8] = b_h1;
    *(half8_t*)&Bl[srow][scol]   = b_l0;  *(half8_t*)&Bl[srow][scol+8] = b_l1;
    __syncthreads();

    half8_t fah[4], fal[4], fbh[4], fbl[4];
    #pragma unroll
    for (int mi = 0; mi < 4; ++mi) {
      fah[mi] = *(const half8_t*)&Ah[ar0 + mi*16][kb];
      fal[mi] = *(const half8_t*)&Al[ar0 + mi*16][kb];
    }
    #pragma unroll
    for (int ni = 0; ni < 4; ++ni) {
      fbh[ni] = *(const half8_t*)&Bh[br0 + ni*16][kb];
      fbl[ni] = *(const half8_t*)&Bl[br0 + ni*16][kb];
    }
    #pragma unroll
    for (int mi = 0; mi < 4; ++mi)
      #pragma unroll
      for (int ni = 0; ni < 4; ++ni) {
        acc[mi][ni] = MFMA_F16(fah[mi], fbh[ni], acc[mi][ni]);
        acc[mi][ni] = MFMA_F16(fal[mi], fbh[ni], acc[mi][ni]);
        acc[mi][ni] = MFMA_F16(fah[mi], fbl[ni], acc[mi][ni]);
      }
  }

  const int rr = (lane >> 4) << 2;
  if (which < 2) {
    _Float16* __restrict__ oh = (which==0) ? qh : kh;
    _Float16* __restrict__ ol = (which==0) ? ql : kl;
    #pragma unroll
    for (int ni = 0; ni < 4; ++ni) {
      const int c = n0 + wn*64 + ni*16 + fr;
      const float bb = bias[c];
      #pragma unroll
      for (int mi = 0; mi < 4; ++mi) {
        const int row0 = m0 + wm*64 + mi*16 + rr;
        #pragma unroll
        for (int j = 0; j < 4; ++j) {
          float r = acc[mi][ni][j] + bb;
          _Float16 hh = (_Float16)r;
          oh[(long)(row0+j)*E_ + c] = hh;
          ol[(long)(row0+j)*E_ + c] = (_Float16)(r - (float)hh);
        }
      }
    }
  } else {
    #pragma unroll
    for (int ni = 0; ni < 4; ++ni) {
      const int c = n0 + wn*64 + ni*16 + fr;
      const int h_ = c >> 6, d_ = c & 63;
      const float bb = bias[c];
      #pragma unroll
      for (int mi = 0; mi < 4; ++mi) {
        const int row0 = m0 + wm*64 + mi*16 + rr;
        #pragma unroll
        for (int j = 0; j < 4; ++j) {
          const int row = row0 + j;
          const int b_ = row >> 10, n_ = row & 1023;
          float r = acc[mi][ni][j] + bb;
          unsigned short hb = f2bf(r);
          const long o = ((long)(b_*H_ + h_)*64 + d_)*N_ + n_;
          vth[o] = hb;
          vtl[o] = f2bf(r - bf2f(hb));
        }
      }
    }
  }
}

// ---------------- Output projection from f16 planes, fp32 out ---------------
__global__ __launch_bounds__(256) void proj_out_kernel(
    const _Float16* __restrict__ ah_g, const _Float16* __restrict__ al_g,
    const _Float16* __restrict__ wh, const _Float16* __restrict__ wl,
    const float* __restrict__ bias, float* __restrict__ out)
{
  __shared__ _Float16 Ah[128][40];
  __shared__ _Float16 Al[128][40];
  __shared__ _Float16 Bh[128][40];
  __shared__ _Float16 Bl[128][40];

  const int tid  = threadIdx.x;
  const int lane = tid & 63;
  const int wv   = tid >> 6;
  const int wm   = wv >> 1, wn = wv & 1;
  const int m0   = blockIdx.y * 128;
  const int n0   = blockIdx.x * 128;

  const int srow = tid >> 1;
  const int scol = (tid & 1) << 4;

  const int gm = m0 + srow;
  const bool aok = gm < M_OUT;
  const long arow = (long)gm * E_ + scol;
  const long brow = (long)(n0 + srow) * E_ + scol;

  f32x4 acc[4][4] = {};

  const int fr = lane & 15;
  const int kb = (lane >> 4) << 3;
  const int ar0 = wm * 64 + fr;
  const int br0 = wn * 64 + fr;

  for (int k0 = 0; k0 < E_; k0 += 32) {
    half8_t a_h0 = {}, a_h1 = {}, a_l0 = {}, a_l1 = {};
    if (aok) {
      a_h0 = *(const half8_t*)&ah_g[arow + k0];
      a_h1 = *(const half8_t*)&ah_g[arow + k0 + 8];
      a_l0 = *(const half8_t*)&al_g[arow + k0];
      a_l1 = *(const half8_t*)&al_g[arow + k0 + 8];
    }
    half8_t b_h0 = *(const half8_t*)&wh[brow + k0];
    half8_t b_h1 = *(const half8_t*)&wh[brow + k0 + 8];
    half8_t b_l0 = *(const half8_t*)&wl[brow + k0];
    half8_t b_l1 = *(const half8_t*)&wl[brow + k0 + 8];
    __syncthreads();
    *(half8_t*)&Ah[srow][scol]   = a_h0;  *(half8_t*)&Ah[srow][scol+8] = a_h1;
    *(half8_t*)&Al[srow][scol]   = a_l0;  *(half8_t*)&Al[srow][scol+8] = a_l1;
    *(half8_t*)&Bh[srow][scol]   = b_h0;  *(half8_t*)&Bh[srow][scol+8] = b_h1;
    *(half8_t*)&Bl[srow][scol]   = b_l0;  *(half8_t*)&Bl[srow][scol+8] = b_l1;
    __syncthreads();

    half8_t fah[4], fal[4], fbh[4], fbl[4];
    #pragma unroll
    for (int mi = 0; mi < 4; ++mi) {
      fah[mi] = *(const half8_t*)&Ah[ar0 + mi*16][kb];
      fal[mi] = *(const half8_t*)&Al[ar0 + mi*16][kb];
    }
    #pragma unroll
    for (int ni = 0; ni < 4; ++ni) {
      fbh[ni] = *(const half8_t*)&Bh[br0 + ni*16][kb];
      fbl[ni] = *(const half8_t*)&Bl[br0 + ni*16][kb];
    }
    #pragma unroll
    for (int mi = 0; mi < 4; ++mi)
      #pragma unroll
      for (int ni = 0; ni < 4; ++ni) {
        acc[mi][ni] = MFMA_F16(fah[mi], fbh[ni], acc[mi][ni]);
        acc[mi][ni] = MFMA_F16(fal[mi], fbh[ni], acc[mi][ni]);
        acc[mi][ni] = MFMA_F16(fah[mi], fbl[ni], acc[mi][ni]);
      }
  }

  const int rr = (lane >> 4) << 2;
  #pragma unroll
  for (int ni = 0; ni < 4; ++ni) {
    const int c = n0 + wn*64 + ni*16 + fr;
    const float bb = bias[c];
    #pragma unroll
    for (int mi = 0; mi < 4; ++mi) {
      const int row = m0 + wm*64 + mi*16 + rr;
      #pragma unroll
      for (int j = 0; j < 4; ++j) {
        if (row + j < M_OUT)
          out[(long)(row + j) * E_ + c] = acc[mi][ni][j] + bb;
      }
    }
  }
}

// ---------------- c = cls @ Wc^T + bc ; cdenom = 1/sqrt(D*clip(|c|^2)) -------
__global__ __launch_bounds__(64) void cls_c_kernel(
    const float* __restrict__ x, const float* __restrict__ Wc, const float* __restrict__ bc,
    float* __restrict__ cbuf, float* __restrict__ cdenom)
{
  const int bh = blockIdx.x;
  const int b = bh / H_, h = bh % H_;
  const int d = threadIdx.x;
  const float* xr = x + (long)b*S_*E_;
  const float* wr = Wc + (long)(h*D_ + d)*E_;
  float acc = 0.f;
  for (int j = 0; j < E_; j += 4) {
    float4 xw = *(const float4*)&xr[j];
    float4 ww = *(const float4*)&wr[j];
    acc += xw.x*ww.x + xw.y*ww.y + xw.z*ww.z + xw.w*ww.w;
  }
  acc += bc[h*D_ + d];
  cbuf[bh*D_ + d] = acc;
  float sq = acc*acc;
  #pragma unroll
  for (int off = 32; off > 0; off >>= 1) sq += __shfl_xor(sq, off);
  if (d == 0) cdenom[bh] = rsqrtf((float)D_ * fmaxf(sq, 1e-5f));
}

// ---------------- main attention: 64x64 tile per block, MFMA -----------------
// All operands arrive pre-split: Q/K f16 planes, V bf16 planes [bh][d][n].
__global__ __launch_bounds__(256) void attn_kernel(
    const _Float16* __restrict__ qh, const _Float16* __restrict__ ql,
    const _Float16* __restrict__ kh, const _Float16* __restrict__ kl,
    const unsigned short* __restrict__ vth, const unsigned short* __restrict__ vtl,
    const float* __restrict__ cbuf, const float* __restrict__ cdenom,
    _Float16* __restrict__ valsh, _Float16* __restrict__ vall,
    float* __restrict__ rowl_g, float* __restrict__ attn)
{
  __shared__ short QPh[64][72];   // Q f16 hi, later P bf16 hi (Q frags in regs)
  __shared__ short QPl[64][72];
  __shared__ short Kh_s[64][72];  // K f16 hi, natural [n][d]
  __shared__ short Kl_s[64][72];
  __shared__ short Vth_s[64][72]; // V bf16 hi, [d][k] (direct copy from vth)
  __shared__ short Vtl_s[64][72];
  __shared__ float cs[64];
  __shared__ float rowscale_s[64];
  __shared__ float rowsum2[2][64];

  const int qt = blockIdx.x, h = blockIdx.y, b = blockIdx.z;
  const int bh = b * H_ + h;
  const int q0 = qt * 64;
  const int tid  = threadIdx.x;
  const int lane = tid & 63;
  const int wv   = tid >> 6;
  const int wm   = wv >> 1, wn = wv & 1;   // 2x2 wave grid, 32x32 per wave
  const int fr   = lane & 15;
  const int g    = lane >> 4;
  const int lr   = tid >> 2;               // staging row 0..63
  const int lc   = (tid & 3) * 16;         // staging col chunk

  // ---- stage Q (copy planes) ----
  {
    const long qbase = ((long)b*N_ + q0 + lr)*E_ + h*D_ + lc;
    *(half8_t*)&QPh[lr][lc]   = *(const half8_t*)&qh[qbase];
    *(half8_t*)&QPh[lr][lc+8] = *(const half8_t*)&qh[qbase+8];
    *(half8_t*)&QPl[lr][lc]   = *(const half8_t*)&ql[qbase];
    *(half8_t*)&QPl[lr][lc+8] = *(const half8_t*)&ql[qbase+8];
  }
  if (tid < 64) cs[tid] = cbuf[bh*D_ + tid];
  const float cdn = cdenom[bh];
  __syncthreads();

  // ---- rowscale ----
  if (tid < 64) {
    const _Float16* qhr = (const _Float16*)QPh[tid];
    const _Float16* qlr = (const _Float16*)QPl[tid];
    float qn2 = 0.f, cq = 0.f;
    #pragma unroll 8
    for (int d = 0; d < 64; ++d) {
      float qv = (float)qhr[d] + (float)qlr[d];
      qn2 = fmaf(qv, qv, qn2);
      cq  = fmaf(cs[d], qv, cq);
    }
    rowscale_s[tid] = cq * cdn / fmaxf(qn2, 1e-5f);
  }

  // ---- preload Q fragments (frees QP buffers for P) ----
  half8_t qfh[2][2], qfl[2][2];
  #pragma unroll
  for (int mi = 0; mi < 2; ++mi)
    #pragma unroll
    for (int ks = 0; ks < 2; ++ks) {
      qfh[mi][ks] = *(const half8_t*)&QPh[wm*32 + mi*16 + fr][ks*32 + g*8];
      qfl[mi][ks] = *(const half8_t*)&QPl[wm*32 + mi*16 + fr][ks*32 + g*8];
    }
  __syncthreads();

  float rs[2][4];
  #pragma unroll
  for (int mi = 0; mi < 2; ++mi)
    #pragma unroll
    for (int j = 0; j < 4; ++j)
      rs[mi][j] = rowscale_s[wm*32 + mi*16 + g*4 + j];

  float psum[2][4] = {};
  f32x4 acc[2][2] = {};

  for (int kt = 0; kt < 16; ++kt) {
    __syncthreads();
    {  // stage K natural [n][d] (copy planes)
      const long kbase = ((long)b*N_ + kt*64 + lr)*E_ + h*D_ + lc;
      *(half8_t*)&Kh_s[lr][lc]   = *(const half8_t*)&kh[kbase];
      *(half8_t*)&Kh_s[lr][lc+8] = *(const half8_t*)&kh[kbase+8];
      *(half8_t*)&Kl_s[lr][lc]   = *(const half8_t*)&kl[kbase];
      *(half8_t*)&Kl_s[lr][lc+8] = *(const half8_t*)&kl[kbase+8];
    }
    {  // stage V [d][k] (direct copy from transposed global planes)
      const long vbase = ((long)bh*64 + lr)*N_ + kt*64 + lc;
      *(short8_t*)&Vth_s[lr][lc]   = *(const short8_t*)(vth + vbase);
      *(short8_t*)&Vth_s[lr][lc+8] = *(const short8_t*)(vth + vbase + 8);
      *(short8_t*)&Vtl_s[lr][lc]   = *(const short8_t*)(vtl + vbase);
      *(short8_t*)&Vtl_s[lr][lc+8] = *(const short8_t*)(vtl + vbase + 8);
    }
    __syncthreads();

    // ---- QK^T (fp16x3) ----
    f32x4 sacc[2][2] = {};
    #pragma unroll
    for (int ks = 0; ks < 2; ++ks) {
      half8_t kfh[2], kfl[2];
      #pragma unroll
      for (int ni = 0; ni < 2; ++ni) {
        kfh[ni] = *(const half8_t*)&Kh_s[wn*32 + ni*16 + fr][ks*32 + g*8];
        kfl[ni] = *(const half8_t*)&Kl_s[wn*32 + ni*16 + fr][ks*32 + g*8];
      }
      #pragma unroll
      for (int mi = 0; mi < 2; ++mi)
        #pragma unroll
        for (int ni = 0; ni < 2; ++ni) {
          sacc[mi][ni] = MFMA_F16(qfh[mi][ks], kfh[ni], sacc[mi][ni]);
          sacc[mi][ni] = MFMA_F16(qfl[mi][ks], kfh[ni], sacc[mi][ni]);
          sacc[mi][ni] = MFMA_F16(qfh[mi][ks], kfl[ni], sacc[mi][ni]);
        }
    }

    // ---- softmax-exp + global store + bf16 split into P buffers ----
    #pragma unroll
    for (int mi = 0; mi < 2; ++mi)
      #pragma unroll
      for (int ni = 0; ni < 2; ++ni)
        #pragma unroll
        for (int j = 0; j < 4; ++j) {
          const int row = wm*32 + mi*16 + g*4 + j;
          const int col = wn*32 + ni*16 + fr;
          float s = sacc[mi][ni][j] * rs[mi][j];
          float p = __expf(fminf(s, 60.f));
          psum[mi][j] += p;
          attn[((long)(bh*N_ + q0 + row) << 10) + kt*64 + col] = p;
          unsigned short hb = f2bf(p);
          QPh[row][col] = (short)hb;
          QPl[row][col] = (short)f2bf(p - bf2f(hb));
        }
    __syncthreads();

    // ---- PV (bf16x3) ----
    #pragma unroll
    for (int ks = 0; ks < 2; ++ks) {
      short8_t pfh[2], pfl[2], vfh[2], vfl[2];
      #pragma unroll
      for (int mi = 0; mi < 2; ++mi) {
        pfh[mi] = *(const short8_t*)&QPh[wm*32 + mi*16 + fr][ks*32 + g*8];
        pfl[mi] = *(const short8_t*)&QPl[wm*32 + mi*16 + fr][ks*32 + g*8];
      }
      #pragma unroll
      for (int nj = 0; nj < 2; ++nj) {
        vfh[nj] = *(const short8_t*)&Vth_s[wn*32 + nj*16 + fr][ks*32 + g*8];
        vfl[nj] = *(const short8_t*)&Vtl_s[wn*32 + nj*16 + fr][ks*32 + g*8];
      }
      #pragma unroll
      for (int mi = 0; mi < 2; ++mi)
        #pragma unroll
        for (int nj = 0; nj < 2; ++nj) {
          acc[mi][nj] = MFMA_BF16(pfh[mi], vfh[nj], acc[mi][nj]);
          acc[mi][nj] = MFMA_BF16(pfl[mi], vfh[nj], acc[mi][nj]);
          acc[mi][nj] = MFMA_BF16(pfh[mi], vfl[nj], acc[mi][nj]);
        }
    }
  }

  // ---- row sums ----
  #pragma unroll
  for (int mi = 0; mi < 2; ++mi)
    #pragma unroll
    for (int j = 0; j < 4; ++j) {
      float v = psum[mi][j];
      v += __shfl_xor(v, 1);
      v += __shfl_xor(v, 2);
      v += __shfl_xor(v, 4);
      v += __shfl_xor(v, 8);
      psum[mi][j] = v;
    }
  __syncthreads();
  if (fr == 0) {
    #pragma unroll
    for (int mi = 0; mi < 2; ++mi)
      #pragma unroll
      for (int j = 0; j < 4; ++j)
        rowsum2[wn][wm*32 + mi*16 + g*4 + j] = psum[mi][j];
  }
  __syncthreads();

  if (tid < 64)
    rowl_g[(long)bh*N_ + q0 + tid] = rowsum2[0][tid] + rowsum2[1][tid];

  // ---- epilogue: O = acc / rowl, written as f16 hi/lo planes ----
  #pragma unroll
  for (int mi = 0; mi < 2; ++mi)
    #pragma unroll
    for (int j = 0; j < 4; ++j) {
      const int row = wm*32 + mi*16 + g*4 + j;
      const float inv = 1.0f / (rowsum2[0][row] + rowsum2[1][row]);
      #pragma unroll
      for (int nj = 0; nj < 2; ++nj) {
        const int col = wn*32 + nj*16 + fr;
        const long vo = ((long)b*S_ + 1 + q0 + row)*E_ + h*D_ + col;
        float r = acc[mi][nj][j] * inv;
        _Float16 hh = (_Float16)r;
        valsh[vo] = hh;
        vall[vo]  = (_Float16)(r - (float)hh);
      }
    }
}

// ---------------- CLS output row (no softmax) --------------------------------
__global__ __launch_bounds__(256) void cls_attn_kernel(
    const float* __restrict__ x,
    const _Float16* __restrict__ kh, const _Float16* __restrict__ kl,
    const unsigned short* __restrict__ vth, const unsigned short* __restrict__ vtl,
    const float* __restrict__ cbuf, const float* __restrict__ cdenom,
    _Float16* __restrict__ valsh, _Float16* __restrict__ vall)
{
  __shared__ float cs[64];
  __shared__ float part[4][64];
  const int bh = blockIdx.x;
  const int b = bh / H_, h = bh % H_;
  const int tid = threadIdx.x;
  const int wv = tid >> 6, lane = tid & 63;
  if (tid < 64) cs[tid] = cbuf[bh*D_ + tid];
  __syncthreads();
  float acc = 0.f;
  const long kbase0 = (long)b*N_*E_ + h*D_ + lane;
  const long vtbase = ((long)bh*64 + lane)*N_;
  for (int kk = wv*256; kk < wv*256 + 256; ++kk) {
    const long kbase = kbase0 + (long)kk*E_;
    float kv = (float)kh[kbase] + (float)kl[kbase];
    float s = cs[lane] * kv;
    s += __shfl_xor(s, 1);  s += __shfl_xor(s, 2);  s += __shfl_xor(s, 4);
    s += __shfl_xor(s, 8);  s += __shfl_xor(s, 16); s += __shfl_xor(s, 32);
    float vvv = bf2f(vth[vtbase + kk]) + bf2f(vtl[vtbase + kk]);
    acc = fmaf(s, vvv, acc);
  }
  part[wv][lane] = acc;
  __syncthreads();
  if (tid < 64) {
    const float tot = (part[0][tid] + part[1][tid] + part[2][tid] + part[3][tid]) * cdenom[bh];
    const float cls = x[(long)b*S_*E_ + h*D_ + tid];
    float r = (cls + tot) * 0.5f;
    const long vo = (long)b*S_*E_ + h*D_ + tid;
    _Float16 hh = (_Float16)r;
    valsh[vo] = hh;
    vall[vo]  = (_Float16)(r - (float)hh);
  }
}

// ---------------- normalize stored attn in place (fp32) ----------------------
__global__ __launch_bounds__(256) void rescale_kernel(
    float* __restrict__ attn, const float* __restrict__ rowl_g)
{
  const long row = blockIdx.x;
  const float inv = 1.0f / rowl_g[row];
  float* p = attn + (row << 10) + threadIdx.x * 4;
  float4 u = *(float4*)p;
  u.x *= inv; u.y *= inv; u.z *= inv; u.w *= inv;
  *(float4*)p = u;
}

extern "C" void kernel_launch(void* const* d_in, const int* in_sizes, int n_in,
                              void* d_out, int out_size, void* d_ws, size_t ws_size,
                              hipStream_t stream) {
  (void)in_sizes; (void)n_in; (void)out_size; (void)ws_size;
  const float* x  = (const float*)d_in[0];
  const float* Wq = (const float*)d_in[1];
  const float* bq = (const float*)d_in[2];
  const float* Wk = (const float*)d_in[3];
  const float* bk = (const float*)d_in[4];
  const float* Wv = (const float*)d_in[5];
  const float* bv = (const float*)d_in[6];
  const float* Wc = (const float*)d_in[7];
  const float* bc = (const float*)d_in[8];
  const float* Wo = (const float*)d_in[9];
  const float* bo = (const float*)d_in[10];

  const long XSZ = (long)8192 * E_;      // 6,291,456
  const long WSZ = (long)E_ * E_;        // 589,824
  const long QSZ = (long)B_ * N_ * E_;   // 6,291,456
  const long VSZ = (long)B_ * S_ * E_;   // 6,297,600

  float* outp = (float*)d_out;
  float* attn = outp + VSZ;              // attn region: 402 MB

  // scratch inside attn region (dead until attn_kernel writes it; stream-ordered)
  _Float16* xh  = (_Float16*)attn;
  _Float16* xl  = xh + XSZ;
  _Float16* wqh = xl + XSZ;
  _Float16* wql = wqh + WSZ;
  _Float16* wkh = wql + WSZ;
  _Float16* wkl = wkh + WSZ;
  _Float16* wvh = wkl + WSZ;
  _Float16* wvl = wvh + WSZ;

  // workspace (~103.5 MB)
  _Float16* qh = (_Float16*)d_ws;
  _Float16* ql = qh + QSZ;
  _Float16* kh = ql + QSZ;
  _Float16* kl = kh + QSZ;
  unsigned short* vth = (unsigned short*)(kl + QSZ);
  unsigned short* vtl = vth + QSZ;
  _Float16* valsh = (_Float16*)(vtl + QSZ);
  _Float16* vall  = valsh + VSZ;
  _Float16* woh   = vall + VSZ;
  _Float16* wol   = woh + WSZ;
  float* cbuf = (float*)(wol + WSZ);
  float* cden = cbuf + B_*H_*D_;
  float* rowl = cden + B_*H_;

  split_x_kernel<<<6144, 256, 0, stream>>>(x, xh, xl);
  split_w_kernel<<<dim3(576, 4), 256, 0, stream>>>(Wq, Wk, Wv, Wo,
      wqh, wql, wkh, wkl, wvh, wvl, woh, wol);
  proj_qkv_kernel<<<dim3(6, 64, 3), 256, 0, stream>>>(xh, xl,
      wqh, wql, wkh, wkl, wvh, wvl, bq, bk, bv, qh, ql, kh, kl, vth, vtl);
  cls_c_kernel<<<B_*H_, 64, 0, stream>>>(x, Wc, bc, cbuf, cden);
  attn_kernel<<<dim3(16, H_, B_), 256, 0, stream>>>(qh, ql, kh, kl, vth, vtl,
      cbuf, cden, valsh, vall, rowl, attn);
  cls_attn_kernel<<<B_*H_, 256, 0, stream>>>(x, kh, kl, vth, vtl, cbuf, cden, valsh, vall);
  rescale_kernel<<<B_*H_*N_, 256, 0, stream>>>(attn, rowl);
  proj_out_kernel<<<dim3(6, 65), 256, 0, stream>>>(valsh, vall, woh, wol, bo, outp);
}

// Round 4
// 934.970 us; speedup vs baseline: 1.1086x; 1.1086x over previous
//
#include <hip/hip_runtime.h>

#define B_ 8
#define S_ 1025
#define E_ 768
#define H_ 12
#define D_ 64
#define N_ 1024
#define M_OUT (B_*S_)   // 8200

typedef _Float16 half8_t __attribute__((ext_vector_type(8)));
typedef _Float16 half4_t __attribute__((ext_vector_type(4)));
typedef short short8_t __attribute__((ext_vector_type(8)));
typedef float f32x4 __attribute__((ext_vector_type(4)));

#define MFMA_F16(A, B, C)  __builtin_amdgcn_mfma_f32_16x16x32_f16((A), (B), (C), 0, 0, 0)
#define MFMA_BF16(A, B, C) __builtin_amdgcn_mfma_f32_16x16x32_bf16((A), (B), (C), 0, 0, 0)

__device__ __forceinline__ unsigned short f2bf(float f) {
  unsigned u = __float_as_uint(f);
  u += 0x7FFFu + ((u >> 16) & 1u);          // RNE
  return (unsigned short)(u >> 16);
}
__device__ __forceinline__ float bf2f(unsigned short s) {
  return __uint_as_float(((unsigned)s) << 16);
}

// ---------------- split x (xt rows, compact) into f16 hi/lo planes ----------
__global__ __launch_bounds__(256) void split_x_kernel(
    const float* __restrict__ x, _Float16* __restrict__ xh, _Float16* __restrict__ xl)
{
  const int idx = blockIdx.x * 256 + threadIdx.x;   // 8192*192 float4s exactly
  const int row = idx / 192;
  const int c   = (idx % 192) * 4;
  const int xrow = row + (row >> 10) + 1;           // skip cls token per batch
  float4 v = *(const float4*)&x[(long)xrow*E_ + c];
  float f[4] = {v.x, v.y, v.z, v.w};
  half4_t hs, ls;
  #pragma unroll
  for (int t = 0; t < 4; ++t) {
    _Float16 hh = (_Float16)f[t];
    hs[t] = hh; ls[t] = (_Float16)(f[t] - (float)hh);
  }
  *(half4_t*)&xh[(long)row*E_ + c] = hs;
  *(half4_t*)&xl[(long)row*E_ + c] = ls;
}

// ---------------- split 4 weight matrices into f16 hi/lo planes -------------
__global__ __launch_bounds__(256) void split_w_kernel(
    const float* __restrict__ W0, const float* __restrict__ W1,
    const float* __restrict__ W2, const float* __restrict__ W3,
    _Float16* __restrict__ h0, _Float16* __restrict__ l0,
    _Float16* __restrict__ h1, _Float16* __restrict__ l1,
    _Float16* __restrict__ h2, _Float16* __restrict__ l2,
    _Float16* __restrict__ h3, _Float16* __restrict__ l3)
{
  const int which = blockIdx.y;
  const float* __restrict__ W = (which==0)?W0:(which==1)?W1:(which==2)?W2:W3;
  _Float16* __restrict__ oh   = (which==0)?h0:(which==1)?h1:(which==2)?h2:h3;
  _Float16* __restrict__ ol   = (which==0)?l0:(which==1)?l1:(which==2)?l2:l3;
  const int idx = blockIdx.x * 256 + threadIdx.x;   // 768*192 float4s exactly
  const long off = (long)idx * 4;
  float4 v = *(const float4*)&W[off];
  float f[4] = {v.x, v.y, v.z, v.w};
  half4_t hs, ls;
  #pragma unroll
  for (int t = 0; t < 4; ++t) {
    _Float16 hh = (_Float16)f[t];
    hs[t] = hh; ls[t] = (_Float16)(f[t] - (float)hh);
  }
  *(half4_t*)&oh[off] = hs;
  *(half4_t*)&ol[off] = ls;
}

// ---------------- QKV projection from f16 planes; split-format outputs ------
// q,k -> f16 hi/lo planes [row][c]; v -> bf16 hi/lo planes transposed [bh][d][n]
// V epilogue goes through LDS (XOR-swizzled) for coalesced 16B stores.
__global__ __launch_bounds__(256) void proj_qkv_kernel(
    const _Float16* __restrict__ xh, const _Float16* __restrict__ xl,
    const _Float16* __restrict__ wqh, const _Float16* __restrict__ wql,
    const _Float16* __restrict__ wkh, const _Float16* __restrict__ wkl,
    const _Float16* __restrict__ wvh, const _Float16* __restrict__ wvl,
    const float* __restrict__ bq, const float* __restrict__ bk, const float* __restrict__ bv,
    _Float16* __restrict__ qh, _Float16* __restrict__ ql,
    _Float16* __restrict__ kh, _Float16* __restrict__ kl,
    unsigned short* __restrict__ vth, unsigned short* __restrict__ vtl)
{
  __shared__ __align__(16) unsigned char smem_raw[40960];
  _Float16 (* const Ah)[40] = (_Float16 (*)[40])(smem_raw);
  _Float16 (* const Al)[40] = (_Float16 (*)[40])(smem_raw + 10240);
  _Float16 (* const Bh)[40] = (_Float16 (*)[40])(smem_raw + 20480);
  _Float16 (* const Bl)[40] = (_Float16 (*)[40])(smem_raw + 30720);

  const int which = blockIdx.z;
  const _Float16* __restrict__ wh = (which==0)?wqh:(which==1)?wkh:wvh;
  const _Float16* __restrict__ wl = (which==0)?wql:(which==1)?wkl:wvl;
  const float* __restrict__ bias  = (which==0)?bq:(which==1)?bk:bv;

  const int tid  = threadIdx.x;
  const int lane = tid & 63;
  const int wv   = tid >> 6;
  const int wm   = wv >> 1, wn = wv & 1;
  const int m0   = blockIdx.y * 128;
  const int n0   = blockIdx.x * 128;

  const int srow = tid >> 1;
  const int scol = (tid & 1) << 4;

  const long arow = (long)(m0 + srow) * E_ + scol;
  const long brow = (long)(n0 + srow) * E_ + scol;

  f32x4 acc[4][4] = {};

  const int fr = lane & 15;
  const int kb = (lane >> 4) << 3;
  const int ar0 = wm * 64 + fr;
  const int br0 = wn * 64 + fr;

  for (int k0 = 0; k0 < E_; k0 += 32) {
    half8_t a_h0 = *(const half8_t*)&xh[arow + k0];
    half8_t a_h1 = *(const half8_t*)&xh[arow + k0 + 8];
    half8_t a_l0 = *(const half8_t*)&xl[arow + k0];
    half8_t a_l1 = *(const half8_t*)&xl[arow + k0 + 8];
    half8_t b_h0 = *(const half8_t*)&wh[brow + k0];
    half8_t b_h1 = *(const half8_t*)&wh[brow + k0 + 8];
    half8_t b_l0 = *(const half8_t*)&wl[brow + k0];
    half8_t b_l1 = *(const half8_t*)&wl[brow + k0 + 8];
    __syncthreads();
    *(half8_t*)&Ah[srow][scol]   = a_h0;  *(half8_t*)&Ah[srow][scol+8] = a_h1;
    *(half8_t*)&Al[srow][scol]   = a_l0;  *(half8_t*)&Al[srow][scol+8] = a_l1;
    *(half8_t*)&Bh[srow][scol]   = b_h0;  *(half8_t*)&Bh[srow][scol+8] = b_h1;
    *(half8_t*)&Bl[srow][scol]   = b_l0;  *(half8_t*)&Bl[srow][scol+8] = b_l1;
    __syncthreads();

    half8_t fah[4], fal[4], fbh[4], fbl[4];
    #pragma unroll
    for (int mi = 0; mi < 4; ++mi) {
      fah[mi] = *(const half8_t*)&Ah[ar0 + mi*16][kb];
      fal[mi] = *(const half8_t*)&Al[ar0 + mi*16][kb];
    }
    #pragma unroll
    for (int ni = 0; ni < 4; ++ni) {
      fbh[ni] = *(const half8_t*)&Bh[br0 + ni*16][kb];
      fbl[ni] = *(const half8_t*)&Bl[br0 + ni*16][kb];
    }
    #pragma unroll
    for (int mi = 0; mi < 4; ++mi)
      #pragma unroll
      for (int ni = 0; ni < 4; ++ni) {
        acc[mi][ni] = MFMA_F16(fah[mi], fbh[ni], acc[mi][ni]);
        acc[mi][ni] = MFMA_F16(fal[mi], fbh[ni], acc[mi][ni]);
        acc[mi][ni] = MFMA_F16(fah[mi], fbl[ni], acc[mi][ni]);
      }
  }

  const int rr = (lane >> 4) << 2;
  if (which < 2) {
    _Float16* __restrict__ oh = (which==0) ? qh : kh;
    _Float16* __restrict__ ol = (which==0) ? ql : kl;
    #pragma unroll
    for (int ni = 0; ni < 4; ++ni) {
      const int c = n0 + wn*64 + ni*16 + fr;
      const float bb = bias[c];
      #pragma unroll
      for (int mi = 0; mi < 4; ++mi) {
        const int row0 = m0 + wm*64 + mi*16 + rr;
        #pragma unroll
        for (int j = 0; j < 4; ++j) {
          float r = acc[mi][ni][j] + bb;
          _Float16 hh = (_Float16)r;
          oh[(long)(row0+j)*E_ + c] = hh;
          ol[(long)(row0+j)*E_ + c] = (_Float16)(r - (float)hh);
        }
      }
    }
  } else {
    // V: transpose through LDS (alias staging buffers), coalesced 16B stores.
    __syncthreads();                        // all frag reads of smem done
    short (* const Vt)[136] = (short (*)[136])(smem_raw);  // 128x136 shorts = 34816B
    const int b_     = m0 >> 10;            // one batch per block (128 | 1024)
    const int n_base = m0 & 1023;
    const int crow = tid >> 1, hf = tid & 1;
    const int cg   = n0 + crow;
    const long obase = ((long)(b_*H_ + (cg >> 6))*64 + (cg & 63))*N_ + n_base + hf*64;
    const int rswz = (crow & 7) << 3;
    #pragma unroll
    for (int plane = 0; plane < 2; ++plane) {
      #pragma unroll
      for (int ni = 0; ni < 4; ++ni) {
        const int cl = wn*64 + ni*16 + fr;
        const float bb = bias[n0 + cl];
        #pragma unroll
        for (int mi = 0; mi < 4; ++mi)
          #pragma unroll
          for (int j = 0; j < 4; ++j) {
            const int rl = wm*64 + mi*16 + rr + j;
            float r = acc[mi][ni][j] + bb;
            unsigned short hb = f2bf(r);
            unsigned short val = plane ? f2bf(r - bf2f(hb)) : hb;
            Vt[cl][rl ^ ((cl & 7) << 3)] = (short)val;
          }
      }
      __syncthreads();
      unsigned short* __restrict__ dst = plane ? vtl : vth;
      #pragma unroll
      for (int t = 0; t < 8; ++t)
        *(short8_t*)&dst[obase + t*8] =
            *(const short8_t*)&Vt[crow][(hf*64 + t*8) ^ rswz];
      __syncthreads();
    }
  }
}

// ---------------- Output projection: fp32 A (in-kernel split) + f16 W planes -
__global__ __launch_bounds__(256) void proj_out_kernel(
    const float* __restrict__ A,
    const _Float16* __restrict__ wh, const _Float16* __restrict__ wl,
    const float* __restrict__ bias, float* __restrict__ out)
{
  __shared__ _Float16 Ah[128][40];
  __shared__ _Float16 Al[128][40];
  __shared__ _Float16 Bh[128][40];
  __shared__ _Float16 Bl[128][40];

  const int tid  = threadIdx.x;
  const int lane = tid & 63;
  const int wv   = tid >> 6;
  const int wm   = wv >> 1, wn = wv & 1;
  const int m0   = blockIdx.y * 128;
  const int n0   = blockIdx.x * 128;

  const int srow = tid >> 1;
  const int scol = (tid & 1) << 4;

  const int gm = m0 + srow;
  const bool aok = gm < M_OUT;
  const long arow = (long)gm * E_ + scol;
  const long brow = (long)(n0 + srow) * E_ + scol;

  f32x4 acc[4][4] = {};

  const int fr = lane & 15;
  const int kb = (lane >> 4) << 3;
  const int ar0 = wm * 64 + fr;
  const int br0 = wn * 64 + fr;

  for (int k0 = 0; k0 < E_; k0 += 32) {
    float4 a0 = make_float4(0.f,0.f,0.f,0.f), a1 = a0, a2 = a0, a3 = a0;
    if (aok) {
      a0 = *(const float4*)&A[arow + k0];
      a1 = *(const float4*)&A[arow + k0 + 4];
      a2 = *(const float4*)&A[arow + k0 + 8];
      a3 = *(const float4*)&A[arow + k0 + 12];
    }
    half8_t b_h0 = *(const half8_t*)&wh[brow + k0];
    half8_t b_h1 = *(const half8_t*)&wh[brow + k0 + 8];
    half8_t b_l0 = *(const half8_t*)&wl[brow + k0];
    half8_t b_l1 = *(const half8_t*)&wl[brow + k0 + 8];
    __syncthreads();
    {
      float av[16] = {a0.x,a0.y,a0.z,a0.w,a1.x,a1.y,a1.z,a1.w,
                      a2.x,a2.y,a2.z,a2.w,a3.x,a3.y,a3.z,a3.w};
      half8_t ah0, ah1, alo0, alo1;
      #pragma unroll
      for (int t = 0; t < 8; ++t) {
        _Float16 hh;
        hh = (_Float16)av[t];   ah0[t] = hh; alo0[t] = (_Float16)(av[t]   - (float)hh);
        hh = (_Float16)av[t+8]; ah1[t] = hh; alo1[t] = (_Float16)(av[t+8] - (float)hh);
      }
      *(half8_t*)&Ah[srow][scol]   = ah0;  *(half8_t*)&Ah[srow][scol+8] = ah1;
      *(half8_t*)&Al[srow][scol]   = alo0; *(half8_t*)&Al[srow][scol+8] = alo1;
    }
    *(half8_t*)&Bh[srow][scol]   = b_h0;  *(half8_t*)&Bh[srow][scol+8] = b_h1;
    *(half8_t*)&Bl[srow][scol]   = b_l0;  *(half8_t*)&Bl[srow][scol+8] = b_l1;
    __syncthreads();

    half8_t fah[4], fal[4], fbh[4], fbl[4];
    #pragma unroll
    for (int mi = 0; mi < 4; ++mi) {
      fah[mi] = *(const half8_t*)&Ah[ar0 + mi*16][kb];
      fal[mi] = *(const half8_t*)&Al[ar0 + mi*16][kb];
    }
    #pragma unroll
    for (int ni = 0; ni < 4; ++ni) {
      fbh[ni] = *(const half8_t*)&Bh[br0 + ni*16][kb];
      fbl[ni] = *(const half8_t*)&Bl[br0 + ni*16][kb];
    }
    #pragma unroll
    for (int mi = 0; mi < 4; ++mi)
      #pragma unroll
      for (int ni = 0; ni < 4; ++ni) {
        acc[mi][ni] = MFMA_F16(fah[mi], fbh[ni], acc[mi][ni]);
        acc[mi][ni] = MFMA_F16(fal[mi], fbh[ni], acc[mi][ni]);
        acc[mi][ni] = MFMA_F16(fah[mi], fbl[ni], acc[mi][ni]);
      }
  }

  const int rr = (lane >> 4) << 2;
  #pragma unroll
  for (int ni = 0; ni < 4; ++ni) {
    const int c = n0 + wn*64 + ni*16 + fr;
    const float bb = bias[c];
    #pragma unroll
    for (int mi = 0; mi < 4; ++mi) {
      const int row = m0 + wm*64 + mi*16 + rr;
      #pragma unroll
      for (int j = 0; j < 4; ++j) {
        if (row + j < M_OUT)
          out[(long)(row + j) * E_ + c] = acc[mi][ni][j] + bb;
      }
    }
  }
}

// ---------------- c = cls @ Wc^T + bc ; cdenom = 1/sqrt(D*clip(|c|^2)) -------
__global__ __launch_bounds__(64) void cls_c_kernel(
    const float* __restrict__ x, const float* __restrict__ Wc, const float* __restrict__ bc,
    float* __restrict__ cbuf, float* __restrict__ cdenom)
{
  const int bh = blockIdx.x;
  const int b = bh / H_, h = bh % H_;
  const int d = threadIdx.x;
  const float* xr = x + (long)b*S_*E_;
  const float* wr = Wc + (long)(h*D_ + d)*E_;
  float acc = 0.f;
  for (int j = 0; j < E_; j += 4) {
    float4 xw = *(const float4*)&xr[j];
    float4 ww = *(const float4*)&wr[j];
    acc += xw.x*ww.x + xw.y*ww.y + xw.z*ww.z + xw.w*ww.w;
  }
  acc += bc[h*D_ + d];
  cbuf[bh*D_ + d] = acc;
  float sq = acc*acc;
  #pragma unroll
  for (int off = 32; off > 0; off >>= 1) sq += __shfl_xor(sq, off);
  if (d == 0) cdenom[bh] = rsqrtf((float)D_ * fmaxf(sq, 1e-5f));
}

// ---------------- main attention: 64x64 tile per block, MFMA, FUSED norm -----
// Phase A: QK^T + exp + rowsum + PV (no attn store).
// Phase B: recompute QK^T (bit-identical) and store NORMALIZED attn directly.
__global__ __launch_bounds__(256) void attn_kernel(
    const _Float16* __restrict__ qh, const _Float16* __restrict__ ql,
    const _Float16* __restrict__ kh, const _Float16* __restrict__ kl,
    const unsigned short* __restrict__ vth, const unsigned short* __restrict__ vtl,
    const float* __restrict__ cbuf, const float* __restrict__ cdenom,
    float* __restrict__ vals, float* __restrict__ attn)
{
  __shared__ short QPh[64][72];   // Q f16 hi, later P bf16 hi (Q frags in regs)
  __shared__ short QPl[64][72];
  __shared__ short Kh_s[64][72];  // K f16 hi, natural [n][d]
  __shared__ short Kl_s[64][72];
  __shared__ short Vth_s[64][72]; // V bf16 hi, [d][k]
  __shared__ short Vtl_s[64][72];
  __shared__ float cs[64];
  __shared__ float rowscale_s[64];
  __shared__ float rowsum2[2][64];

  const int qt = blockIdx.x, h = blockIdx.y, b = blockIdx.z;
  const int bh = b * H_ + h;
  const int q0 = qt * 64;
  const int tid  = threadIdx.x;
  const int lane = tid & 63;
  const int wv   = tid >> 6;
  const int wm   = wv >> 1, wn = wv & 1;   // 2x2 wave grid, 32x32 per wave
  const int fr   = lane & 15;
  const int g    = lane >> 4;
  const int lr   = tid >> 2;               // staging row 0..63
  const int lc   = (tid & 3) * 16;         // staging col chunk

  // ---- stage Q (copy planes) ----
  {
    const long qbase = ((long)b*N_ + q0 + lr)*E_ + h*D_ + lc;
    *(half8_t*)&QPh[lr][lc]   = *(const half8_t*)&qh[qbase];
    *(half8_t*)&QPh[lr][lc+8] = *(const half8_t*)&qh[qbase+8];
    *(half8_t*)&QPl[lr][lc]   = *(const half8_t*)&ql[qbase];
    *(half8_t*)&QPl[lr][lc+8] = *(const half8_t*)&ql[qbase+8];
  }
  if (tid < 64) cs[tid] = cbuf[bh*D_ + tid];
  const float cdn = cdenom[bh];
  __syncthreads();

  // ---- rowscale ----
  if (tid < 64) {
    const _Float16* qhr = (const _Float16*)QPh[tid];
    const _Float16* qlr = (const _Float16*)QPl[tid];
    float qn2 = 0.f, cq = 0.f;
    #pragma unroll 8
    for (int d = 0; d < 64; ++d) {
      float qv = (float)qhr[d] + (float)qlr[d];
      qn2 = fmaf(qv, qv, qn2);
      cq  = fmaf(cs[d], qv, cq);
    }
    rowscale_s[tid] = cq * cdn / fmaxf(qn2, 1e-5f);
  }

  // ---- preload Q fragments (frees QP buffers for P) ----
  half8_t qfh[2][2], qfl[2][2];
  #pragma unroll
  for (int mi = 0; mi < 2; ++mi)
    #pragma unroll
    for (int ks = 0; ks < 2; ++ks) {
      qfh[mi][ks] = *(const half8_t*)&QPh[wm*32 + mi*16 + fr][ks*32 + g*8];
      qfl[mi][ks] = *(const half8_t*)&QPl[wm*32 + mi*16 + fr][ks*32 + g*8];
    }
  __syncthreads();

  float rs[2][4];
  #pragma unroll
  for (int mi = 0; mi < 2; ++mi)
    #pragma unroll
    for (int j = 0; j < 4; ++j)
      rs[mi][j] = rowscale_s[wm*32 + mi*16 + g*4 + j];

  float psum[2][4] = {};
  f32x4 acc[2][2] = {};

  // ================= PHASE A: denominators + PV =================
  for (int kt = 0; kt < 16; ++kt) {
    __syncthreads();
    {  // stage K natural [n][d] (copy planes)
      const long kbase = ((long)b*N_ + kt*64 + lr)*E_ + h*D_ + lc;
      *(half8_t*)&Kh_s[lr][lc]   = *(const half8_t*)&kh[kbase];
      *(half8_t*)&Kh_s[lr][lc+8] = *(const half8_t*)&kh[kbase+8];
      *(half8_t*)&Kl_s[lr][lc]   = *(const half8_t*)&kl[kbase];
      *(half8_t*)&Kl_s[lr][lc+8] = *(const half8_t*)&kl[kbase+8];
    }
    {  // stage V [d][k] (direct copy from transposed global planes)
      const long vbase = ((long)bh*64 + lr)*N_ + kt*64 + lc;
      *(short8_t*)&Vth_s[lr][lc]   = *(const short8_t*)(vth + vbase);
      *(short8_t*)&Vth_s[lr][lc+8] = *(const short8_t*)(vth + vbase + 8);
      *(short8_t*)&Vtl_s[lr][lc]   = *(const short8_t*)(vtl + vbase);
      *(short8_t*)&Vtl_s[lr][lc+8] = *(const short8_t*)(vtl + vbase + 8);
    }
    __syncthreads();

    // ---- QK^T (fp16x3) ----
    f32x4 sacc[2][2] = {};
    #pragma unroll
    for (int ks = 0; ks < 2; ++ks) {
      half8_t kfh[2], kfl[2];
      #pragma unroll
      for (int ni = 0; ni < 2; ++ni) {
        kfh[ni] = *(const half8_t*)&Kh_s[wn*32 + ni*16 + fr][ks*32 + g*8];
        kfl[ni] = *(const half8_t*)&Kl_s[wn*32 + ni*16 + fr][ks*32 + g*8];
      }
      #pragma unroll
      for (int mi = 0; mi < 2; ++mi)
        #pragma unroll
        for (int ni = 0; ni < 2; ++ni) {
          sacc[mi][ni] = MFMA_F16(qfh[mi][ks], kfh[ni], sacc[mi][ni]);
          sacc[mi][ni] = MFMA_F16(qfl[mi][ks], kfh[ni], sacc[mi][ni]);
          sacc[mi][ni] = MFMA_F16(qfh[mi][ks], kfl[ni], sacc[mi][ni]);
        }
    }

    // ---- exp + psum + bf16 split into P buffers (NO global store) ----
    #pragma unroll
    for (int mi = 0; mi < 2; ++mi)
      #pragma unroll
      for (int ni = 0; ni < 2; ++ni)
        #pragma unroll
        for (int j = 0; j < 4; ++j) {
          const int row = wm*32 + mi*16 + g*4 + j;
          const int col = wn*32 + ni*16 + fr;
          float s = sacc[mi][ni][j] * rs[mi][j];
          float p = __expf(fminf(s, 60.f));
          psum[mi][j] += p;
          unsigned short hb = f2bf(p);
          QPh[row][col] = (short)hb;
          QPl[row][col] = (short)f2bf(p - bf2f(hb));
        }
    __syncthreads();

    // ---- PV (bf16x3) ----
    #pragma unroll
    for (int ks = 0; ks < 2; ++ks) {
      short8_t pfh[2], pfl[2], vfh[2], vfl[2];
      #pragma unroll
      for (int mi = 0; mi < 2; ++mi) {
        pfh[mi] = *(const short8_t*)&QPh[wm*32 + mi*16 + fr][ks*32 + g*8];
        pfl[mi] = *(const short8_t*)&QPl[wm*32 + mi*16 + fr][ks*32 + g*8];
      }
      #pragma unroll
      for (int nj = 0; nj < 2; ++nj) {
        vfh[nj] = *(const short8_t*)&Vth_s[wn*32 + nj*16 + fr][ks*32 + g*8];
        vfl[nj] = *(const short8_t*)&Vtl_s[wn*32 + nj*16 + fr][ks*32 + g*8];
      }
      #pragma unroll
      for (int mi = 0; mi < 2; ++mi)
        #pragma unroll
        for (int nj = 0; nj < 2; ++nj) {
          acc[mi][nj] = MFMA_BF16(pfh[mi], vfh[nj], acc[mi][nj]);
          acc[mi][nj] = MFMA_BF16(pfl[mi], vfh[nj], acc[mi][nj]);
          acc[mi][nj] = MFMA_BF16(pfh[mi], vfl[nj], acc[mi][nj]);
        }
    }
  }

  // ---- row sums ----
  #pragma unroll
  for (int mi = 0; mi < 2; ++mi)
    #pragma unroll
    for (int j = 0; j < 4; ++j) {
      float v = psum[mi][j];
      v += __shfl_xor(v, 1);
      v += __shfl_xor(v, 2);
      v += __shfl_xor(v, 4);
      v += __shfl_xor(v, 8);
      psum[mi][j] = v;
    }
  __syncthreads();
  if (fr == 0) {
    #pragma unroll
    for (int mi = 0; mi < 2; ++mi)
      #pragma unroll
      for (int j = 0; j < 4; ++j)
        rowsum2[wn][wm*32 + mi*16 + g*4 + j] = psum[mi][j];
  }
  __syncthreads();

  // per-thread inverse row sums
  float invr[2][4];
  #pragma unroll
  for (int mi = 0; mi < 2; ++mi)
    #pragma unroll
    for (int j = 0; j < 4; ++j) {
      const int row = wm*32 + mi*16 + g*4 + j;
      invr[mi][j] = 1.0f / (rowsum2[0][row] + rowsum2[1][row]);
    }

  // ---- O = acc / rowl, fp32 ----
  #pragma unroll
  for (int mi = 0; mi < 2; ++mi)
    #pragma unroll
    for (int j = 0; j < 4; ++j) {
      const int row = wm*32 + mi*16 + g*4 + j;
      #pragma unroll
      for (int nj = 0; nj < 2; ++nj) {
        const int col = wn*32 + nj*16 + fr;
        vals[((long)b*S_ + 1 + q0 + row)*E_ + h*D_ + col] = acc[mi][nj][j] * invr[mi][j];
      }
    }

  // ================= PHASE B: recompute + store normalized attn =============
  for (int kt = 0; kt < 16; ++kt) {
    __syncthreads();
    {  // restage K (L2-hot second read)
      const long kbase = ((long)b*N_ + kt*64 + lr)*E_ + h*D_ + lc;
      *(half8_t*)&Kh_s[lr][lc]   = *(const half8_t*)&kh[kbase];
      *(half8_t*)&Kh_s[lr][lc+8] = *(const half8_t*)&kh[kbase+8];
      *(half8_t*)&Kl_s[lr][lc]   = *(const half8_t*)&kl[kbase];
      *(half8_t*)&Kl_s[lr][lc+8] = *(const half8_t*)&kl[kbase+8];
    }
    __syncthreads();

    f32x4 sacc[2][2] = {};
    #pragma unroll
    for (int ks = 0; ks < 2; ++ks) {
      half8_t kfh[2], kfl[2];
      #pragma unroll
      for (int ni = 0; ni < 2; ++ni) {
        kfh[ni] = *(const half8_t*)&Kh_s[wn*32 + ni*16 + fr][ks*32 + g*8];
        kfl[ni] = *(const half8_t*)&Kl_s[wn*32 + ni*16 + fr][ks*32 + g*8];
      }
      #pragma unroll
      for (int mi = 0; mi < 2; ++mi)
        #pragma unroll
        for (int ni = 0; ni < 2; ++ni) {
          sacc[mi][ni] = MFMA_F16(qfh[mi][ks], kfh[ni], sacc[mi][ni]);
          sacc[mi][ni] = MFMA_F16(qfl[mi][ks], kfh[ni], sacc[mi][ni]);
          sacc[mi][ni] = MFMA_F16(qfh[mi][ks], kfl[ni], sacc[mi][ni]);
        }
    }

    #pragma unroll
    for (int mi = 0; mi < 2; ++mi)
      #pragma unroll
      for (int ni = 0; ni < 2; ++ni)
        #pragma unroll
        for (int j = 0; j < 4; ++j) {
          const int row = wm*32 + mi*16 + g*4 + j;
          const int col = wn*32 + ni*16 + fr;
          float s = sacc[mi][ni][j] * rs[mi][j];
          float p = __expf(fminf(s, 60.f));   // bit-identical to phase A
          attn[((long)(bh*N_ + q0 + row) << 10) + kt*64 + col] = p * invr[mi][j];
        }
  }
}

// ---------------- CLS output row (no softmax) --------------------------------
__global__ __launch_bounds__(256) void cls_attn_kernel(
    const float* __restrict__ x,
    const _Float16* __restrict__ kh, const _Float16* __restrict__ kl,
    const unsigned short* __restrict__ vth, const unsigned short* __restrict__ vtl,
    const float* __restrict__ cbuf, const float* __restrict__ cdenom,
    float* __restrict__ vals)
{
  __shared__ float cs[64];
  __shared__ float part[4][64];
  const int bh = blockIdx.x;
  const int b = bh / H_, h = bh % H_;
  const int tid = threadIdx.x;
  const int wv = tid >> 6, lane = tid & 63;
  if (tid < 64) cs[tid] = cbuf[bh*D_ + tid];
  __syncthreads();
  float acc = 0.f;
  const long kbase0 = (long)b*N_*E_ + h*D_ + lane;
  const long vtbase = ((long)bh*64 + lane)*N_;
  for (int kk = wv*256; kk < wv*256 + 256; ++kk) {
    const long kbase = kbase0 + (long)kk*E_;
    float kv = (float)kh[kbase] + (float)kl[kbase];
    float s = cs[lane] * kv;
    s += __shfl_xor(s, 1);  s += __shfl_xor(s, 2);  s += __shfl_xor(s, 4);
    s += __shfl_xor(s, 8);  s += __shfl_xor(s, 16); s += __shfl_xor(s, 32);
    float vvv = bf2f(vth[vtbase + kk]) + bf2f(vtl[vtbase + kk]);
    acc = fmaf(s, vvv, acc);
  }
  part[wv][lane] = acc;
  __syncthreads();
  if (tid < 64) {
    const float tot = (part[0][tid] + part[1][tid] + part[2][tid] + part[3][tid]) * cdenom[bh];
    const float cls = x[(long)b*S_*E_ + h*D_ + tid];
    vals[(long)b*S_*E_ + h*D_ + tid] = (cls + tot) * 0.5f;
  }
}

extern "C" void kernel_launch(void* const* d_in, const int* in_sizes, int n_in,
                              void* d_out, int out_size, void* d_ws, size_t ws_size,
                              hipStream_t stream) {
  (void)in_sizes; (void)n_in; (void)out_size; (void)ws_size;
  const float* x  = (const float*)d_in[0];
  const float* Wq = (const float*)d_in[1];
  const float* bq = (const float*)d_in[2];
  const float* Wk = (const float*)d_in[3];
  const float* bk = (const float*)d_in[4];
  const float* Wv = (const float*)d_in[5];
  const float* bv = (const float*)d_in[6];
  const float* Wc = (const float*)d_in[7];
  const float* bc = (const float*)d_in[8];
  const float* Wo = (const float*)d_in[9];
  const float* bo = (const float*)d_in[10];

  const long XSZ = (long)8192 * E_;      // 6,291,456
  const long WSZ = (long)E_ * E_;        // 589,824
  const long QSZ = (long)B_ * N_ * E_;   // 6,291,456
  const long VSZ = (long)B_ * S_ * E_;   // 6,297,600

  float* outp = (float*)d_out;
  float* attn = outp + VSZ;              // attn region: 402 MB

  // scratch inside attn region (dead until attn_kernel phase B writes it)
  _Float16* xh  = (_Float16*)attn;
  _Float16* xl  = xh + XSZ;
  _Float16* wqh = xl + XSZ;
  _Float16* wql = wqh + WSZ;
  _Float16* wkh = wql + WSZ;
  _Float16* wkl = wkh + WSZ;
  _Float16* wvh = wkl + WSZ;
  _Float16* wvl = wvh + WSZ;

  // workspace (~103 MB)
  _Float16* qh = (_Float16*)d_ws;
  _Float16* ql = qh + QSZ;
  _Float16* kh = ql + QSZ;
  _Float16* kl = kh + QSZ;
  unsigned short* vth = (unsigned short*)(kl + QSZ);
  unsigned short* vtl = vth + QSZ;
  float* vals = (float*)(vtl + QSZ);
  _Float16* woh = (_Float16*)(vals + VSZ);
  _Float16* wol = woh + WSZ;
  float* cbuf = (float*)(wol + WSZ);
  float* cden = cbuf + B_*H_*D_;

  split_x_kernel<<<6144, 256, 0, stream>>>(x, xh, xl);
  split_w_kernel<<<dim3(576, 4), 256, 0, stream>>>(Wq, Wk, Wv, Wo,
      wqh, wql, wkh, wkl, wvh, wvl, woh, wol);
  proj_qkv_kernel<<<dim3(6, 64, 3), 256, 0, stream>>>(xh, xl,
      wqh, wql, wkh, wkl, wvh, wvl, bq, bk, bv, qh, ql, kh, kl, vth, vtl);
  cls_c_kernel<<<B_*H_, 64, 0, stream>>>(x, Wc, bc, cbuf, cden);
  attn_kernel<<<dim3(16, H_, B_), 256, 0, stream>>>(qh, ql, kh, kl, vth, vtl,
      cbuf, cden, vals, attn);
  cls_attn_kernel<<<B_*H_, 256, 0, stream>>>(x, kh, kl, vth, vtl, cbuf, cden, vals);
  proj_out_kernel<<<dim3(6, 65), 256, 0, stream>>>(vals, woh, wol, bo, outp);
}